// Round 2
// baseline (460.355 us; speedup 1.0000x reference)
//
#include <hip/hip_runtime.h>
#include <hip/hip_cooperative_groups.h>
#include <math.h>

namespace cg = cooperative_groups;

#define N_NODES 50000
#define N_EDGES 800000
#define HIDDEN  64
#define NPART   500                   // partition chunks
#define PCHUNK  1600                  // edges per partition chunk (500*1600 = 800000)
#define NBUCK   32
#define SLICE   1568                  // 32*1568 = 50176 >= 50000
#define CAPB    128                   // per-(block,bucket) stage cap
#define BCAP    26000                 // dense bucket capacity
#define NSUB    16                    // agg sub-blocks per bucket -> 512 agg blocks
#define GRID    512                   // cooperative grid: 2 blocks/CU on 256 CUs

// Fused single cooperative kernel. Phases separated by grid.sync():
//  P0 zero deg+tails | P1 partition + global deg atomics | P2 dinv,g |
//  P3 agg1 -> part1  | P4 reduce+MLP -> z | P5 agg2 -> part2 | P6 final -> out

__global__ __launch_bounds__(256, 2)
void k_fused(const int* __restrict__ row, const int* __restrict__ col,
             const float* __restrict__ x,
             const float* __restrict__ W1, const float* __restrict__ b1,
             const float* __restrict__ W2, const float* __restrict__ b2,
             unsigned* __restrict__ tails, unsigned* __restrict__ bks,
             unsigned* __restrict__ deg,
             float* __restrict__ dinv, float* __restrict__ g,
             float* __restrict__ part1, float2* __restrict__ z,
             float2* __restrict__ part2, float2* __restrict__ out)
{
    cg::grid_group grid = cg::this_grid();
    const int t   = threadIdx.x;
    const int blk = blockIdx.x;

    // one raw LDS pool reused across phases:
    // P1: stage[4096] + cnt[32] + gpos[32]   (16.6 KB)
    // P3: acc f32[1568]                      (6.3 KB)
    // P5: ax f32[1568] + ay f32[1568]        (12.5 KB)
    __shared__ unsigned shraw[NBUCK * CAPB + 2 * NBUCK];

    // ---- P0: zero deg + tails (workspace is poisoned by harness) ----
    {
        int i = blk * 256 + t;
        if (i < N_NODES) deg[i] = 0u;
        if (blk == 0 && t < NBUCK) tails[t] = 0u;
    }
    grid.sync();

    // ---- P1: radix partition + global degree atomics ----
    {
        unsigned* stage = shraw;
        unsigned* cnt   = shraw + NBUCK * CAPB;
        unsigned* gpos  = cnt + NBUCK;
        if (blk < NPART) {
            if (t < NBUCK) cnt[t] = 0u;
            __syncthreads();
            const int e0 = blk * PCHUNK;
            const int4* c4 = (const int4*)(col + e0);
            const int4* r4 = (const int4*)(row + e0);
            for (int i = t; i < PCHUNK / 4; i += 256) {
                int4 cv = c4[i];
                int4 rv = r4[i];
#pragma unroll
                for (int k = 0; k < 4; ++k) {
                    int c = (&cv.x)[k], r = (&rv.x)[k];
                    atomicAdd(&deg[c], 1u);             // fire-and-forget, L2-resident
                    int b = c / SLICE;                  // magic-mul div
                    unsigned off = atomicAdd(&cnt[b], 1u);
                    if (off < CAPB)
                        stage[(b << 7) + off] = ((unsigned)(c - b * SLICE) << 16) | (unsigned)r;
                }
            }
            __syncthreads();
            if (t < NBUCK) {
                unsigned cc = min(cnt[t], (unsigned)CAPB);
                cnt[t] = cc;
                gpos[t] = atomicAdd(&tails[t], cc);
            }
            __syncthreads();
            for (int i = t; i < NBUCK * CAPB; i += 256) {
                int b = i >> 7; unsigned o = (unsigned)(i & 127);
                if (o < cnt[b]) {
                    unsigned dst = gpos[b] + o;
                    if (dst < BCAP) bks[(size_t)b * BCAP + dst] = stage[i];
                }
            }
        }
    }
    grid.sync();

    // ---- P2: dinv = rsqrt(deg+1), g = dinv * x ----
    {
        int n = blk * 256 + t;
        if (n < N_NODES) {
            float di = rsqrtf((float)(deg[n] + 1u));    // +1 self-loop
            dinv[n] = di;
            g[n] = di * x[n];
        }
    }
    grid.sync();

    // ---- P3: layer-1 aggregation -> part1 ----
    {
        float* acc = (float*)shraw;
        const int b = blk >> 4;
        const int s = blk & (NSUB - 1);
        for (int i = t; i < SLICE; i += 256) acc[i] = 0.0f;
        __syncthreads();
        unsigned tail  = min(tails[b], (unsigned)BCAP);
        unsigned chunk = (tail + NSUB - 1) / NSUB;
        unsigned lo = s * chunk, hi = min(lo + chunk, tail);
        const unsigned* bk = bks + (size_t)b * BCAP;
        for (unsigned i = lo + t; i < hi; i += 256) {
            unsigned v = bk[i];                         // coalesced
            atomicAdd(&acc[v >> 16], g[v & 0xFFFFu]);   // LDS atomic + L2 gather
        }
        __syncthreads();
        float* dst = part1 + (size_t)blk * SLICE;
        for (int i = t; i < SLICE; i += 256) dst[i] = acc[i];
    }
    grid.sync();

    // ---- P4: reduce NSUB partials + fused MLP -> z ----
    {
        int n = blk * 256 + t;
        if (n < N_NODES) {
            int b = n / SLICE, cl = n - b * SLICE;
            const float* p = part1 + (size_t)b * NSUB * SLICE + cl;
            float tt = 0.0f;
#pragma unroll
            for (int s2 = 0; s2 < NSUB; ++s2) tt += p[(size_t)s2 * SLICE];
            float di = dinv[n];
            float sv = di * (tt + g[n]);
            float y0 = 0.0f, y1 = 0.0f;
#pragma unroll
            for (int k = 0; k < HIDDEN; ++k) {          // wave-uniform -> s_load
                float h = fmaxf(sv * W1[k] + b1[k], 0.0f);
                y0 += h * W2[2 * k];
                y1 += h * W2[2 * k + 1];
            }
            z[n] = make_float2(di * y0, di * y1);
        }
    }
    grid.sync();

    // ---- P5: layer-2 aggregation (float2) -> part2 ----
    {
        float* ax = (float*)shraw;
        float* ay = ax + SLICE;
        const int b = blk >> 4;
        const int s = blk & (NSUB - 1);
        for (int i = t; i < SLICE; i += 256) { ax[i] = 0.0f; ay[i] = 0.0f; }
        __syncthreads();
        unsigned tail  = min(tails[b], (unsigned)BCAP);
        unsigned chunk = (tail + NSUB - 1) / NSUB;
        unsigned lo = s * chunk, hi = min(lo + chunk, tail);
        const unsigned* bk = bks + (size_t)b * BCAP;
        for (unsigned i = lo + t; i < hi; i += 256) {
            unsigned v = bk[i];
            float2 zz = z[v & 0xFFFFu];
            unsigned cl = v >> 16;
            atomicAdd(&ax[cl], zz.x);
            atomicAdd(&ay[cl], zz.y);
        }
        __syncthreads();
        float2* dst = part2 + (size_t)blk * SLICE;
        for (int i = t; i < SLICE; i += 256) dst[i] = make_float2(ax[i], ay[i]);
    }
    grid.sync();

    // ---- P6: reduce float2 partials + epilogue -> out ----
    {
        int n = blk * 256 + t;
        if (n < N_NODES) {
            int b = n / SLICE, cl = n - b * SLICE;
            const float2* p = part2 + (size_t)b * NSUB * SLICE + cl;
            float Tx = 0.0f, Ty = 0.0f;
#pragma unroll
            for (int s2 = 0; s2 < NSUB; ++s2) {
                float2 v = p[(size_t)s2 * SLICE];
                Tx += v.x; Ty += v.y;
            }
            float di = dinv[n];
            float2 zn = z[n];
            out[n] = make_float2(di * (Tx + zn.x) + b2[0], di * (Ty + zn.y) + b2[1]);
        }
    }
}

// ================= launch =================

extern "C" void kernel_launch(void* const* d_in, const int* in_sizes, int n_in,
                              void* d_out, int out_size, void* d_ws, size_t ws_size,
                              hipStream_t stream) {
    const float* x  = (const float*)d_in[0];
    const int*   ei = (const int*)d_in[1];
    const float* W1 = (const float*)d_in[2];
    const float* b1 = (const float*)d_in[3];
    const float* W2 = (const float*)d_in[4];
    const float* b2 = (const float*)d_in[5];

    const int* row = ei;
    const int* col = ei + N_EDGES;

    char* p = (char*)d_ws;
    unsigned* tails = (unsigned*)p;  p += 128;
    unsigned* bks   = (unsigned*)p;  p += (size_t)NBUCK * BCAP * 4;                // 3.3 MB
    unsigned* deg   = (unsigned*)p;  p += 200064;                                  // 50000*4 padded
    float*    part1 = (float*)p;     p += (size_t)NBUCK * NSUB * SLICE * 4;        // 3.2 MB
    float2*   part2 = (float2*)p;    p += (size_t)NBUCK * NSUB * SLICE * 8;        // 6.4 MB
    float*    dinv  = (float*)p;     p += 200064;
    float*    g     = (float*)p;     p += 200064;
    float2*   z     = (float2*)p;

    float2* out = (float2*)d_out;

    void* args[] = { (void*)&row, (void*)&col, (void*)&x,
                     (void*)&W1, (void*)&b1, (void*)&W2, (void*)&b2,
                     (void*)&tails, (void*)&bks, (void*)&deg,
                     (void*)&dinv, (void*)&g, (void*)&part1, (void*)&z,
                     (void*)&part2, (void*)&out };

    hipLaunchCooperativeKernel((void*)k_fused, dim3(GRID), dim3(256), args, 0, stream);
}

// Round 3
// 112.019 us; speedup vs baseline: 4.1096x; 4.1096x over previous
//
#include <hip/hip_runtime.h>
#include <math.h>

#define N_NODES 50000
#define N_EDGES 800000
#define HIDDEN  64
#define NPART   500                   // partition blocks
#define PCHUNK  1600                  // edges per partition block
#define NBUCK   32
#define SLICE   1568                  // 32*1568 = 50176 >= 50000
#define CAPB    128                   // per-(block,bucket) stage cap
#define BCAP    26000                 // dense bucket capacity
#define NSUB    16                    // agg sub-blocks per bucket -> 512 agg blocks (2/CU)

// NOTE (R2 post-mortem): cooperative grid.sync costs ~50us/sync on this stack at 512 WGs,
// and scattered device-scope atomics add ~25MB RMW traffic — fused single-kernel was 3.4x
// slower. Multi-kernel graph replay has ~1-2us gaps; poison fills (~82us) dominate the wall.

// ---- K1: write-combined radix partition, DENSE flush via bucket-tail reservation ----
__global__ __launch_bounds__(256)
void k_part(const int* __restrict__ row, const int* __restrict__ col,
            unsigned* __restrict__ tails, unsigned* __restrict__ bks) {
    __shared__ unsigned stage[NBUCK * CAPB];        // 16 KB
    __shared__ unsigned cnt2[NBUCK], gpos[NBUCK];
    const int t   = threadIdx.x;
    const int blk = blockIdx.x;
    const int e0  = blk * PCHUNK;
    if (t < NBUCK) cnt2[t] = 0u;
    __syncthreads();
    const int4* c4 = (const int4*)(col + e0);
    const int4* r4 = (const int4*)(row + e0);
    for (int i = t; i < PCHUNK / 4; i += 256) {     // 400 int4s
        int4 cv = c4[i];
        int4 rv = r4[i];
#pragma unroll
        for (int k = 0; k < 4; ++k) {
            int c = (&cv.x)[k], r = (&rv.x)[k];
            int b = c / SLICE;                      // magic-mul div
            unsigned off = atomicAdd(&cnt2[b], 1u);
            if (off < CAPB)
                stage[(b << 7) + off] = ((unsigned)(c - b * SLICE) << 16) | (unsigned)r;
        }
    }
    __syncthreads();
    if (t < NBUCK) {
        unsigned cc = min(cnt2[t], (unsigned)CAPB);
        cnt2[t] = cc;
        gpos[t] = atomicAdd(&tails[t], cc);
    }
    __syncthreads();
    for (int i = t; i < NBUCK * CAPB; i += 256) {
        int b = i >> 7; unsigned o = (unsigned)(i & 127);
        if (o < cnt2[b]) {
            unsigned dst = gpos[b] + o;
            if (dst < BCAP) bks[(size_t)b * BCAP + dst] = stage[i];
        }
    }
}

// chunk bounds for a sub-block, 4-aligned so uint4 loads stay aligned
__device__ __forceinline__ void sub_range(unsigned tail, int s, unsigned& lo, unsigned& hi) {
    unsigned chunk = ((tail + NSUB - 1) / NSUB + 3u) & ~3u;
    lo = s * chunk;
    hi = min(lo + chunk, tail);
    if (lo > tail) lo = tail;
}

// ---- K2: per-slice degree partials (uint4 reads) ----
__global__ __launch_bounds__(256)
void k_deg(const unsigned* __restrict__ tails, const unsigned* __restrict__ bks,
           unsigned* __restrict__ part_deg) {
    __shared__ unsigned acc[SLICE];                 // 6.3 KB
    const int b = blockIdx.x >> 4;
    const int s = blockIdx.x & (NSUB - 1);
    for (int i = threadIdx.x; i < SLICE; i += 256) acc[i] = 0u;
    __syncthreads();
    unsigned tail = min(tails[b], (unsigned)BCAP);
    unsigned lo, hi; sub_range(tail, s, lo, hi);
    const unsigned* bk = bks + (size_t)b * BCAP;
    const uint4* bk4 = (const uint4*)bk;
    unsigned hiv = hi & ~3u;
    for (unsigned i = (lo >> 2) + threadIdx.x; (i << 2) < hiv; i += 256) {
        uint4 v4 = bk4[i];
#pragma unroll
        for (int k = 0; k < 4; ++k) atomicAdd(&acc[(&v4.x)[k] >> 16], 1u);
    }
    for (unsigned i = hiv + threadIdx.x; i < hi; i += 256)
        atomicAdd(&acc[bk[i] >> 16], 1u);
    __syncthreads();
    unsigned* dst = part_deg + (size_t)blockIdx.x * SLICE;
    for (int i = threadIdx.x; i < SLICE; i += 256) dst[i] = acc[i];
}

// ---- K3: reduce NSUB degree partials -> dinv, g = rsqrt(deg+1)*x ----
__global__ __launch_bounds__(256)
void k_g(const unsigned* __restrict__ part_deg, const float* __restrict__ x,
         float* __restrict__ dinv, float* __restrict__ g) {
    int n = blockIdx.x * 256 + threadIdx.x;
    if (n >= N_NODES) return;
    int b = n / SLICE, cl = n - b * SLICE;
    const unsigned* p = part_deg + (size_t)b * NSUB * SLICE + cl;
    unsigned deg = 0;
#pragma unroll
    for (int s = 0; s < NSUB; ++s) deg += p[(size_t)s * SLICE];
    float di = rsqrtf((float)(deg + 1));            // +1 self-loop
    dinv[n] = di;
    g[n] = di * x[n];
}

// ---- K4: layer-1 aggregation (uint4 reads -> 4 outstanding gathers/lane) ----
__global__ __launch_bounds__(256)
void k_agg1(const unsigned* __restrict__ tails, const unsigned* __restrict__ bks,
            const float* __restrict__ g, float* __restrict__ part1) {
    __shared__ float acc[SLICE];
    const int b = blockIdx.x >> 4;
    const int s = blockIdx.x & (NSUB - 1);
    for (int i = threadIdx.x; i < SLICE; i += 256) acc[i] = 0.0f;
    __syncthreads();
    unsigned tail = min(tails[b], (unsigned)BCAP);
    unsigned lo, hi; sub_range(tail, s, lo, hi);
    const unsigned* bk = bks + (size_t)b * BCAP;
    const uint4* bk4 = (const uint4*)bk;
    unsigned hiv = hi & ~3u;
    for (unsigned i = (lo >> 2) + threadIdx.x; (i << 2) < hiv; i += 256) {
        uint4 v4 = bk4[i];
        float g0 = g[v4.x & 0xFFFFu];
        float g1 = g[v4.y & 0xFFFFu];
        float g2 = g[v4.z & 0xFFFFu];
        float g3 = g[v4.w & 0xFFFFu];
        atomicAdd(&acc[v4.x >> 16], g0);
        atomicAdd(&acc[v4.y >> 16], g1);
        atomicAdd(&acc[v4.z >> 16], g2);
        atomicAdd(&acc[v4.w >> 16], g3);
    }
    for (unsigned i = hiv + threadIdx.x; i < hi; i += 256) {
        unsigned v = bk[i];
        atomicAdd(&acc[v >> 16], g[v & 0xFFFFu]);
    }
    __syncthreads();
    float* dst = part1 + (size_t)blockIdx.x * SLICE;
    for (int i = threadIdx.x; i < SLICE; i += 256) dst[i] = acc[i];
}

// ---- K5: reduce NSUB partials + fused MLP -> z ----
__global__ __launch_bounds__(256)
void k_mlp(const float* __restrict__ part1, const float* __restrict__ g,
           const float* __restrict__ dinv,
           const float* __restrict__ W1, const float* __restrict__ b1,
           const float* __restrict__ W2, float2* __restrict__ z) {
    int n = blockIdx.x * 256 + threadIdx.x;
    if (n >= N_NODES) return;
    int b = n / SLICE, cl = n - b * SLICE;
    const float* p = part1 + (size_t)b * NSUB * SLICE + cl;
    float t = 0.0f;
#pragma unroll
    for (int s = 0; s < NSUB; ++s) t += p[(size_t)s * SLICE];
    float di = dinv[n];
    float sv = di * (t + g[n]);
    float y0 = 0.0f, y1 = 0.0f;
#pragma unroll
    for (int k = 0; k < HIDDEN; ++k) {              // wave-uniform -> s_load
        float h = fmaxf(sv * W1[k] + b1[k], 0.0f);
        y0 += h * W2[2 * k];
        y1 += h * W2[2 * k + 1];
    }
    z[n] = make_float2(di * y0, di * y1);
}

// ---- K6: layer-2 aggregation (float2, uint4 reads) ----
__global__ __launch_bounds__(256)
void k_agg2(const unsigned* __restrict__ tails, const unsigned* __restrict__ bks,
            const float2* __restrict__ z, float2* __restrict__ part2) {
    __shared__ float ax[SLICE];
    __shared__ float ay[SLICE];
    const int b = blockIdx.x >> 4;
    const int s = blockIdx.x & (NSUB - 1);
    for (int i = threadIdx.x; i < SLICE; i += 256) { ax[i] = 0.0f; ay[i] = 0.0f; }
    __syncthreads();
    unsigned tail = min(tails[b], (unsigned)BCAP);
    unsigned lo, hi; sub_range(tail, s, lo, hi);
    const unsigned* bk = bks + (size_t)b * BCAP;
    const uint4* bk4 = (const uint4*)bk;
    unsigned hiv = hi & ~3u;
    for (unsigned i = (lo >> 2) + threadIdx.x; (i << 2) < hiv; i += 256) {
        uint4 v4 = bk4[i];
        float2 z0 = z[v4.x & 0xFFFFu];
        float2 z1 = z[v4.y & 0xFFFFu];
        float2 z2 = z[v4.z & 0xFFFFu];
        float2 z3 = z[v4.w & 0xFFFFu];
        atomicAdd(&ax[v4.x >> 16], z0.x); atomicAdd(&ay[v4.x >> 16], z0.y);
        atomicAdd(&ax[v4.y >> 16], z1.x); atomicAdd(&ay[v4.y >> 16], z1.y);
        atomicAdd(&ax[v4.z >> 16], z2.x); atomicAdd(&ay[v4.z >> 16], z2.y);
        atomicAdd(&ax[v4.w >> 16], z3.x); atomicAdd(&ay[v4.w >> 16], z3.y);
    }
    for (unsigned i = hiv + threadIdx.x; i < hi; i += 256) {
        unsigned v = bk[i];
        float2 zz = z[v & 0xFFFFu];
        atomicAdd(&ax[v >> 16], zz.x);
        atomicAdd(&ay[v >> 16], zz.y);
    }
    __syncthreads();
    float2* dst = part2 + (size_t)blockIdx.x * SLICE;
    for (int i = threadIdx.x; i < SLICE; i += 256) dst[i] = make_float2(ax[i], ay[i]);
}

// ---- K7: reduce NSUB float2 partials + epilogue -> out ----
__global__ __launch_bounds__(256)
void k_final(const float2* __restrict__ part2, const float2* __restrict__ z,
             const float* __restrict__ dinv, const float* __restrict__ b2,
             float2* __restrict__ out) {
    int n = blockIdx.x * 256 + threadIdx.x;
    if (n >= N_NODES) return;
    int b = n / SLICE, cl = n - b * SLICE;
    const float2* p = part2 + (size_t)b * NSUB * SLICE + cl;
    float Tx = 0.0f, Ty = 0.0f;
#pragma unroll
    for (int s = 0; s < NSUB; ++s) {
        float2 v = p[(size_t)s * SLICE];
        Tx += v.x; Ty += v.y;
    }
    float di = dinv[n];
    float2 zn = z[n];
    out[n] = make_float2(di * (Tx + zn.x) + b2[0], di * (Ty + zn.y) + b2[1]);
}

// ================= launch =================

extern "C" void kernel_launch(void* const* d_in, const int* in_sizes, int n_in,
                              void* d_out, int out_size, void* d_ws, size_t ws_size,
                              hipStream_t stream) {
    const float* x  = (const float*)d_in[0];
    const int*   ei = (const int*)d_in[1];
    const float* W1 = (const float*)d_in[2];
    const float* b1 = (const float*)d_in[3];
    const float* W2 = (const float*)d_in[4];
    const float* b2 = (const float*)d_in[5];

    const int* row = ei;
    const int* col = ei + N_EDGES;

    char* p = (char*)d_ws;
    unsigned* tails    = (unsigned*)p;  p += 128;
    unsigned* bks      = (unsigned*)p;  p += (size_t)NBUCK * BCAP * 4;             // 3.3 MB
    unsigned* part_deg = (unsigned*)p;  p += (size_t)NBUCK * NSUB * SLICE * 4;     // 3.2 MB
    float*    part1    = (float*)p;     p += (size_t)NBUCK * NSUB * SLICE * 4;     // 3.2 MB
    float2*   part2    = (float2*)p;    p += (size_t)NBUCK * NSUB * SLICE * 8;     // 6.4 MB
    float*    dinv     = (float*)p;     p += 200064;
    float*    g        = (float*)p;     p += 200064;
    float2*   z        = (float2*)p;

    const int gA = NBUCK * NSUB;            // 512 agg blocks (2 per CU)
    const int gN = (N_NODES + 255) / 256;   // 196

    hipMemsetAsync(tails, 0, NBUCK * sizeof(unsigned), stream);
    k_part <<<NPART, 256, 0, stream>>>(row, col, tails, bks);
    k_deg  <<<gA,    256, 0, stream>>>(tails, bks, part_deg);
    k_g    <<<gN,    256, 0, stream>>>(part_deg, x, dinv, g);
    k_agg1 <<<gA,    256, 0, stream>>>(tails, bks, g, part1);
    k_mlp  <<<gN,    256, 0, stream>>>(part1, g, dinv, W1, b1, W2, z);
    k_agg2 <<<gA,    256, 0, stream>>>(tails, bks, z, part2);
    k_final<<<gN,    256, 0, stream>>>(part2, z, dinv, b2, (float2*)d_out);
}